// Round 1
// baseline (364.114 us; speedup 1.0000x reference)
//
#include <hip/hip_runtime.h>
#include <hip/hip_cooperative_groups.h>

namespace cg = cooperative_groups;

constexpr int IN_DIM   = 128;
constexpr int OUT_DIM  = 64;
constexpr int EDGE_DIM = 16;
constexpr int BS       = 8;
constexpr int NN       = 512;
constexpr int ROWS     = BS * NN;   // 4096
constexpr int TI       = 4;         // attention rows per tile
constexpr int BLOCKS   = 512;       // 2 tiles per block; 8 fc rows per block

// Phase A scratch: x rows + W staged with padded stride (33 float4 per row
// -> bank phase (o+k)&7, <=2-way on ds_read_b128, i.e. conflict-free).
struct SmemA {
    float  xs[8 * IN_DIM];          // 4 KB
    float4 ws[64 * 33];             // 33 KB
};
// Phase B scratch.
struct SmemB {
    float  sjb[NN];                 // 2 KB : s_j for the whole batch row-block
    float  alpha[TI * NN];          // 8 KB : e (pass1) then normalized alpha
    float4 part[TI][16][16];        // 16 KB: phase-3 partial sums
};

__global__ __launch_bounds__(256, 2) void gat_fused(
    const float* __restrict__ x, const float* __restrict__ edge,
    const float* __restrict__ W, const float* __restrict__ attn_w,
    float* __restrict__ out)
{
    __shared__ union { SmemA a; SmemB b; } sm;   // 37 KB -> 2 blocks/CU

    const int t    = threadIdx.x;
    const int lane = t & 63;
    const int w    = t >> 6;           // wave id 0..3
    const int blk  = blockIdx.x;

    // ---------------- Phase A: h = x @ W^T  (rows blk*8 .. +7) -> out -----
    {
        const int rowBase = blk * 8;
        ((float4*)sm.a.xs)[t] = ((const float4*)(x + (size_t)rowBase * IN_DIM))[t];
        const float4* W4 = (const float4*)W;     // 2048 float4
        #pragma unroll
        for (int i = 0; i < 8; ++i) {
            const int s = t + i * 256;           // coalesced global read
            sm.a.ws[(s >> 5) * 33 + (s & 31)] = W4[s];
        }
        __syncthreads();
        const float4* xr0 = (const float4*)&sm.a.xs[(w * 2 + 0) * IN_DIM];
        const float4* xr1 = (const float4*)&sm.a.xs[(w * 2 + 1) * IN_DIM];
        float acc0 = 0.f, acc1 = 0.f;
        #pragma unroll 8
        for (int k = 0; k < IN_DIM / 4; ++k) {
            const float4 wv = sm.a.ws[lane * 33 + k];   // LDS, ~conflict-free
            const float4 x0 = xr0[k];                   // broadcast
            const float4 x1 = xr1[k];
            acc0 += x0.x * wv.x + x0.y * wv.y + x0.z * wv.z + x0.w * wv.w;
            acc1 += x1.x * wv.x + x1.y * wv.y + x1.z * wv.z + x1.w * wv.w;
        }
        out[(size_t)(rowBase + w * 2 + 0) * OUT_DIM + lane] = acc0;
        out[(size_t)(rowBase + w * 2 + 1) * OUT_DIM + lane] = acc1;
    }

    cg::this_grid().sync();   // h complete everywhere; also fences LDS reuse

    // ---------------- Phase B: attention, h read from `out` ---------------
    const int b = blk >> 6;                               // batch
    const float4* h4 = (const float4*)(out + (((size_t)b) << 9) * OUT_DIM);
    const int o4 = t & 15;                                // float4 chunk of 64
    const int g  = t >> 4;                                // 16 j-groups

    // B1: sjb[j] = h[b,j,:] . a_j   (s_i dropped: softmax shift-invariant)
    {
        const float4 aj = ((const float4*)attn_w)[OUT_DIM / 4 + o4];
        for (int it = 0; it < 32; ++it) {
            const int j = it * 16 + g;
            const float4 hv = h4[j * 16 + o4];            // coalesced, L2-hot
            float p = hv.x * aj.x + hv.y * aj.y + hv.z * aj.z + hv.w * aj.w;
            p += __shfl_xor(p, 1, 64);
            p += __shfl_xor(p, 2, 64);
            p += __shfl_xor(p, 4, 64);
            p += __shfl_xor(p, 8, 64);
            if (o4 == 0) sm.b.sjb[j] = p;
        }
    }

    const float4* ae4 = (const float4*)(attn_w + 2 * OUT_DIM);
    const float4 aesel = ae4[lane & 3];     // each lane only needs its quarter
    float4 vt0 = make_float4(0.f, 0.f, 0.f, 0.f);
    float4 vt1 = make_float4(0.f, 0.f, 0.f, 0.f);

    #pragma unroll
    for (int tile = 0; tile < 2; ++tile) {
        __syncthreads();   // sjb ready (tile 0) / part reads done (tile 1)

        const int    iRow = ((blk & 63) * 2 + tile) * TI + w;  // wave's row
        const size_t rowg = (((size_t)b) << 9) + iRow;
        const float4* ef4 = (const float4*)edge + rowg * (NN * EDGE_DIM / 4);

        // pass 1: fully-coalesced edge stream (1 KiB contiguous per wave
        // instruction), 4-lane reduce for the 16-wide dot, e -> alpha row.
        float m = -1e30f;
        #pragma unroll 4
        for (int jj = 0; jj < 32; ++jj) {
            const float4 v = ef4[jj * 64 + lane];   // lane-consecutive float4
            float pd = v.x * aesel.x + v.y * aesel.y + v.z * aesel.z + v.w * aesel.w;
            pd += __shfl_xor(pd, 1, 64);
            pd += __shfl_xor(pd, 2, 64);            // sum over the 4 quarters
            const int jloc = jj * 16 + (lane >> 2);
            const float ev = pd + sm.b.sjb[jloc];
            m = fmaxf(m, ev);
            if ((lane & 3) == 0) sm.b.alpha[w * NN + jloc] = ev;
        }
        #pragma unroll
        for (int msk = 32; msk > 0; msk >>= 1) m = fmaxf(m, __shfl_xor(m, msk, 64));

        // pass 2: softmax normalize from own wave's LDS row (wave-ordered)
        float p[8], s = 0.f;
        #pragma unroll
        for (int jj = 0; jj < 8; ++jj) {
            p[jj] = __expf(sm.b.alpha[w * NN + jj * 64 + lane] - m);
            s += p[jj];
        }
        #pragma unroll
        for (int msk = 32; msk > 0; msk >>= 1) s += __shfl_xor(s, msk, 64);
        const float rinv = 1.0f / s;
        #pragma unroll
        for (int jj = 0; jj < 8; ++jj)
            sm.b.alpha[w * NN + jj * 64 + lane] = p[jj] * rinv;

        __syncthreads();

        // B3: out[r,:] = sum_j alpha[r][j] * h[b,j,:]  (h read once/block)
        float4 acc[TI];
        #pragma unroll
        for (int r = 0; r < TI; ++r) acc[r] = make_float4(0.f, 0.f, 0.f, 0.f);
        #pragma unroll 4
        for (int j = g; j < NN; j += 16) {
            const float4 hv = h4[j * 16 + o4];
            #pragma unroll
            for (int r = 0; r < TI; ++r) {
                const float a = sm.b.alpha[r * NN + j];   // 16-lane broadcast
                acc[r].x += a * hv.x; acc[r].y += a * hv.y;
                acc[r].z += a * hv.z; acc[r].w += a * hv.w;
            }
        }
        #pragma unroll
        for (int r = 0; r < TI; ++r) sm.b.part[r][g][o4] = acc[r];
        __syncthreads();

        float4 vv = make_float4(0.f, 0.f, 0.f, 0.f);
        if (t < 64) {
            const int r = t >> 4, c = t & 15;
            vv = sm.b.part[r][0][c];
            #pragma unroll
            for (int g2 = 1; g2 < 16; ++g2) {
                const float4 q = sm.b.part[r][g2][c];
                vv.x += q.x; vv.y += q.y; vv.z += q.z; vv.w += q.w;
            }
        }
        if (tile == 0) vt0 = vv; else vt1 = vv;
    }

    cg::this_grid().sync();   // every block done READING h from `out`

    if (t < 64) {
        const int r = t >> 4, c = t & 15;
        const size_t obase = ((size_t)b) << 9;
        const int i0 = ((blk & 63) * 2 + 0) * TI + r;
        const int i1 = ((blk & 63) * 2 + 1) * TI + r;
        ((float4*)out)[(obase + i0) * 16 + c] = vt0;
        ((float4*)out)[(obase + i1) * 16 + c] = vt1;
    }
}

extern "C" void kernel_launch(void* const* d_in, const int* in_sizes, int n_in,
                              void* d_out, int out_size, void* d_ws, size_t ws_size,
                              hipStream_t stream) {
    const float* x      = (const float*)d_in[0];
    const float* edge   = (const float*)d_in[1];
    const float* W_fc   = (const float*)d_in[2];
    const float* attn_w = (const float*)d_in[3];
    float* out = (float*)d_out;

    // Zero workspace bytes touched: h lives inside `out` between grid syncs.
    void* args[] = { (void*)&x, (void*)&edge, (void*)&W_fc, (void*)&attn_w, (void*)&out };
    hipLaunchCooperativeKernel((const void*)gat_fused, dim3(BLOCKS), dim3(256),
                               args, 0, stream);
}

// Round 2
// 205.066 us; speedup vs baseline: 1.7756x; 1.7756x over previous
//
#include <hip/hip_runtime.h>

constexpr int IN_DIM   = 128;
constexpr int OUT_DIM  = 64;
constexpr int EDGE_DIM = 16;
constexpr int BS       = 8;
constexpr int NN       = 512;
constexpr int ROWS     = BS * NN;   // 4096
constexpr int TI       = 4;         // attention rows per block

// ---------------------------------------------------------------------------
// Kernel 1: h = x @ W^T  (h row-major (ROWS,64)),  s_j = h · a_j
// 512 blocks x 256 threads; wave handles 2 rows (lane = output dim o).
// W staged in LDS with 33-float4 padded stride: bank-quad start = 4*o mod 32
// -> 8 requests/bank uniform = ds_read_b128 throughput floor (no conflict).
// s_i is dropped: softmax over j is invariant to the per-i constant.
// ---------------------------------------------------------------------------
__global__ __launch_bounds__(256, 4) void fc_kernel(
    const float* __restrict__ x, const float* __restrict__ W,
    const float* __restrict__ attn_w,
    float* __restrict__ h, float* __restrict__ sj)
{
    __shared__ float  xs[8 * IN_DIM];   // 4 KB
    __shared__ float4 ws[64 * 33];      // 33.8 KB (padded W)
    const int t    = threadIdx.x;
    const int lane = t & 63;
    const int w    = t >> 6;
    const int rowBase = blockIdx.x * 8;

    ((float4*)xs)[t] = ((const float4*)(x + (size_t)rowBase * IN_DIM))[t];
    const float4* W4 = (const float4*)W;          // 2048 float4, coalesced
    #pragma unroll
    for (int i = 0; i < 8; ++i) {
        const int s = t + i * 256;
        ws[(s >> 5) * 33 + (s & 31)] = W4[s];
    }
    const float a_j = attn_w[OUT_DIM + lane];
    __syncthreads();

    const float4* xr0 = (const float4*)&xs[(w * 2 + 0) * IN_DIM];
    const float4* xr1 = (const float4*)&xs[(w * 2 + 1) * IN_DIM];
    float acc0 = 0.f, acc1 = 0.f;
    #pragma unroll 8
    for (int k = 0; k < IN_DIM / 4; ++k) {
        const float4 wv = ws[lane * 33 + k];      // LDS, conflict-floor
        const float4 x0 = xr0[k];                 // broadcast (free)
        const float4 x1 = xr1[k];
        acc0 += x0.x * wv.x + x0.y * wv.y + x0.z * wv.z + x0.w * wv.w;
        acc1 += x1.x * wv.x + x1.y * wv.y + x1.z * wv.z + x1.w * wv.w;
    }
    #pragma unroll
    for (int r = 0; r < 2; ++r) {
        const float a   = r ? acc1 : acc0;
        const int   row = rowBase + w * 2 + r;
        h[(size_t)row * OUT_DIM + lane] = a;      // coalesced 256 B/wave
        float pj = a * a_j;
        #pragma unroll
        for (int m = 32; m > 0; m >>= 1) pj += __shfl_xor(pj, m, 64);
        if (lane == 0) sj[row] = pj;
    }
}

// ---------------------------------------------------------------------------
// Kernel 2: TI=4 rows i per block; wave w owns row i_base+w.
// s_j staged once into LDS. Phase-1 edge stream with 16 loads in flight
// (unroll 4). Wave-local softmax via shfl (no barriers). Phase-3 reads h
// once per block; final reduce parallel across all 4 waves.
// ---------------------------------------------------------------------------
__global__ __launch_bounds__(256, 4) void attn_kernel(
    const float* __restrict__ edge, const float* __restrict__ attn_w,
    const float* __restrict__ h, const float* __restrict__ sj,
    float* __restrict__ out)
{
    __shared__ float  sjb[NN];            // 2 KB
    __shared__ float  alpha[TI * NN];     // 8 KB (normalized alpha)
    __shared__ float4 part[TI][16][16];   // 16 KB

    const int t    = threadIdx.x;
    const int lane = t & 63;
    const int w    = t >> 6;              // wave = local row r
    const int blk  = blockIdx.x;          // b*128 + itile
    const int b    = blk >> 7;
    const int iRow = (blk & 127) * TI + w;
    const size_t rowg = ((size_t)b << 9) + iRow;

    if (t < 128)                          // stage s_j for the whole batch
        ((float4*)sjb)[t] = ((const float4*)(sj + ((size_t)b << 9)))[t];

    const float4* ae4 = (const float4*)(attn_w + 2 * OUT_DIM);
    const float4 ae0 = ae4[0], ae1 = ae4[1], ae2 = ae4[2], ae3 = ae4[3];
    const float4* ef4 = (const float4*)edge + rowg * (NN * EDGE_DIM / 4);
    __syncthreads();

    // ---- phase 1: e_j for j = jj*64 + lane; 16 loads in flight ----
    float e[8];
    #pragma unroll 4
    for (int jj = 0; jj < 8; ++jj) {
        const int j = jj * 64 + lane;
        const float4 v0 = ef4[j * 4 + 0], v1 = ef4[j * 4 + 1];
        const float4 v2 = ef4[j * 4 + 2], v3 = ef4[j * 4 + 3];
        const float se = v0.x * ae0.x + v0.y * ae0.y + v0.z * ae0.z + v0.w * ae0.w
                       + v1.x * ae1.x + v1.y * ae1.y + v1.z * ae1.z + v1.w * ae1.w
                       + v2.x * ae2.x + v2.y * ae2.y + v2.z * ae2.z + v2.w * ae2.w
                       + v3.x * ae3.x + v3.y * ae3.y + v3.z * ae3.z + v3.w * ae3.w;
        e[jj] = sjb[j] + se;              // stride-1 LDS: 2-way = free
    }

    // ---- wave-local softmax ----
    float m = e[0];
    #pragma unroll
    for (int jj = 1; jj < 8; ++jj) m = fmaxf(m, e[jj]);
    #pragma unroll
    for (int msk = 32; msk > 0; msk >>= 1) m = fmaxf(m, __shfl_xor(m, msk, 64));

    float p[8], s = 0.f;
    #pragma unroll
    for (int jj = 0; jj < 8; ++jj) { p[jj] = __expf(e[jj] - m); s += p[jj]; }
    #pragma unroll
    for (int msk = 32; msk > 0; msk >>= 1) s += __shfl_xor(s, msk, 64);
    const float rinv = 1.0f / s;
    #pragma unroll
    for (int jj = 0; jj < 8; ++jj)
        alpha[w * NN + jj * 64 + lane] = p[jj] * rinv;

    __syncthreads();

    // ---- phase 3: out[r,:] = sum_j alpha[r][j] * h[b,j,:], h read once ----
    const int o4 = t & 15;                // float4 chunk of 64-dim output
    const int g  = t >> 4;                // 16 groups over j
    const float4* h4 = (const float4*)(h + (((size_t)b) << 9) * OUT_DIM);
    float4 acc[TI];
    #pragma unroll
    for (int r = 0; r < TI; ++r) acc[r] = make_float4(0.f, 0.f, 0.f, 0.f);
    #pragma unroll 4
    for (int j = g; j < NN; j += 16) {
        const float4 hv = h4[j * 16 + o4];
        #pragma unroll
        for (int r = 0; r < TI; ++r) {
            const float a = alpha[r * NN + j];   // 16-lane broadcast
            acc[r].x += a * hv.x; acc[r].y += a * hv.y;
            acc[r].z += a * hv.z; acc[r].w += a * hv.w;
        }
    }
    #pragma unroll
    for (int r = 0; r < TI; ++r) part[r][g][o4] = acc[r];
    __syncthreads();

    // ---- final reduce: all 4 waves participate (wave w -> row w) ----
    {
        const int c = lane & 15;          // output float4 chunk
        const int q = lane >> 4;          // quarter of the 16 groups
        float4 v = part[w][q * 4 + 0][c];
        #pragma unroll
        for (int i = 1; i < 4; ++i) {
            const float4 u = part[w][q * 4 + i][c];
            v.x += u.x; v.y += u.y; v.z += u.z; v.w += u.w;
        }
        #pragma unroll
        for (int msk = 16; msk <= 32; msk <<= 1) {
            v.x += __shfl_xor(v.x, msk, 64);
            v.y += __shfl_xor(v.y, msk, 64);
            v.z += __shfl_xor(v.z, msk, 64);
            v.w += __shfl_xor(v.w, msk, 64);
        }
        if (q == 0)
            ((float4*)out)[rowg * 16 + c] = v;   // 256 B/wave coalesced
    }
}

extern "C" void kernel_launch(void* const* d_in, const int* in_sizes, int n_in,
                              void* d_out, int out_size, void* d_ws, size_t ws_size,
                              hipStream_t stream) {
    const float* x      = (const float*)d_in[0];
    const float* edge   = (const float*)d_in[1];
    const float* W_fc   = (const float*)d_in[2];
    const float* attn_w = (const float*)d_in[3];
    float* out = (float*)d_out;

    float* h  = (float*)d_ws;                   // ROWS*64 floats = 1 MiB
    float* sj = h + (size_t)ROWS * OUT_DIM;     // 16 KB

    fc_kernel<<<ROWS / 8, 256, 0, stream>>>(x, W_fc, attn_w, h, sj);
    attn_kernel<<<ROWS / TI, 256, 0, stream>>>(edge, attn_w, h, sj, out);
}